// Round 3
// baseline (253.116 us; speedup 1.0000x reference)
//
#include <hip/hip_runtime.h>
#include <math.h>
#include <stdint.h>

#define NRAYS 8000
#define NB 2
#define GX 200
#define GY 200
#define GZ 16
#define BGRID (GX*GY*GZ)
#define NCH 18
#define FREE_ID 17
#define NWAVES (NB*NRAYS)
#define BLOCK 1024
#define WPB (BLOCK/64)
#define NBLOCKS (NWAVES/WPB)   // 1000

// ---------------- host: replicate _ray_constants() exactly ----------------
namespace {

struct MT19937 {
  uint32_t mt[624]; int mti;
  void seed(uint32_t s){
    mt[0]=s;
    for (mti=1; mti<624; ++mti)
      mt[mti] = 1812433253u*(mt[mti-1]^(mt[mti-1]>>30)) + (uint32_t)mti;
  }
  uint32_t next(){
    if (mti >= 624){
      for (int i=0;i<624;i++){
        uint32_t y = (mt[i]&0x80000000u) | (mt[(i+1)%624]&0x7fffffffu);
        mt[i] = mt[(i+397)%624] ^ (y>>1) ^ ((y&1u)? 2567483615u : 0u);
      }
      mti = 0;
    }
    uint32_t y = mt[mti++];
    y ^= y>>11; y ^= (y<<7)&2636928640u; y ^= (y<<15)&4022730752u; y ^= y>>18;
    return y;
  }
};

static uint32_t rinterval(MT19937& g, uint32_t mx){
  if (mx==0) return 0;
  uint32_t mask=mx; mask|=mask>>1; mask|=mask>>2; mask|=mask>>4; mask|=mask>>8; mask|=mask>>16;
  uint32_t v;
  do { v = g.next()&mask; } while (v>mx);
  return v;
}

static int build_table(float4* out){
  double pitch[128]; int npi=0;
  for (int k=0;k<10;k++) pitch[npi++] = -(M_PI/2.0 - atan((double)(k+1)));
  while (pitch[npi-1] < 0.21){
    double d = pitch[npi-1]-pitch[npi-2];
    pitch[npi] = pitch[npi-1]+d; ++npi;
  }
  int nrays = npi*360;   // 39*360 = 14040
  static float rx[128*360], ry[128*360], rz[128*360], rdt[128*360];
  float dtmin = 1e30f;
  for (int p=0;p<npi;p++){
    double cp = cos(pitch[p]), sp = sin(pitch[p]);
    for (int a=0;a<360;a++){
      double az = (double)a * (M_PI/180.0);
      int i = p*360+a;
      rx[i]=(float)(cp*cos(az)); ry[i]=(float)(cp*sin(az)); rz[i]=(float)sp;
      float ma = fmaxf(fabsf(rx[i]), fmaxf(fabsf(ry[i]), fabsf(rz[i])));
      ma = ma + 1e-8f;
      rdt[i] = 0.4f/ma;
      if (rdt[i] < dtmin) dtmin = rdt[i];
    }
  }
  int smax = (int)fmin(ceil(60.0/(double)dtmin), 512.0);
  static int perm[128*360];
  for (int i=0;i<nrays;i++) perm[i]=i;
  MT19937 g; g.seed(0);
  for (int i=nrays-1;i>=1;--i){
    uint32_t j = rinterval(g, (uint32_t)i);
    int tmp = perm[i]; perm[i]=perm[j]; perm[j]=tmp;
  }
  for (int i=0;i<NRAYS;i++){
    int id = perm[i];
    out[i] = make_float4(rx[id], ry[id], rz[id], rdt[id]);
  }
  return smax;
}

// Built once at library load (input-independent constant, like the reference's
// module-level _DIRS/_DT). Device copy allocated+filled OUTSIDE kernel_launch
// and outside graph capture, so the graph needs no H2D node.
struct TabHolder {
  float4* h;        // pinned (or pageable fallback) host copy
  float4* d;        // persistent device copy (null -> fallback path)
  int smax;
  TabHolder(){
    h = nullptr; d = nullptr;
    if (hipHostMalloc((void**)&h, sizeof(float4)*NRAYS, 0) != hipSuccess || !h){
      static float4 fb[NRAYS]; h = fb;
    }
    smax = build_table(h);
    float4* dp = nullptr;
    if (hipMalloc((void**)&dp, sizeof(float4)*NRAYS) == hipSuccess && dp){
      if (hipMemcpy(dp, h, sizeof(float4)*NRAYS, hipMemcpyHostToDevice) == hipSuccess)
        d = dp;
    }
  }
};
static TabHolder g_tab;

} // namespace

// ---------------- device ----------------

// step geometry; separately-rounded mul/add/div to match the reference exactly
__device__ inline void probe(float ox,float oy,float oz,const float4& rd,
                             int s,int S,int& flat,bool& tok,bool& inb)
{
  float t = __fmul_rn(rd.w, (float)s + 0.5f);
  tok = (s < S) && (t <= 60.0f);
  float px = __fadd_rn(ox, __fmul_rn(rd.x, t));
  float py = __fadd_rn(oy, __fmul_rn(rd.y, t));
  float pz = __fadd_rn(oz, __fmul_rn(rd.z, t));
  int vx = (int)floorf(__fdiv_rn(__fadd_rn(px, 40.0f), 0.4f));
  int vy = (int)floorf(__fdiv_rn(__fadd_rn(py, 40.0f), 0.4f));
  int vz = (int)floorf(__fdiv_rn(__fadd_rn(pz, 1.0f), 0.4f));
  flat = (vx*GY+vy)*GZ+vz;
  inb = tok & ((unsigned)vx < (unsigned)GX) & ((unsigned)vy < (unsigned)GY)
            & ((unsigned)vz < (unsigned)GZ);
}

__device__ inline void lse18(const float* __restrict__ lg, float& mx, float& ls){
  float m = lg[0];
  #pragma unroll
  for (int c=1;c<NCH;c++) m = fmaxf(m, lg[c]);
  float s = 0.f;
  #pragma unroll
  for (int c=0;c<NCH;c++) s += expf(lg[c]-m);
  mx = m; ls = logf(s);
}

__global__ __launch_bounds__(BLOCK) void ray_loss_kernel(
    const float* __restrict__ logits, const float* __restrict__ origins,
    const int* __restrict__ sem, const int* __restrict__ cam,
    const float4* __restrict__ rays, float* __restrict__ partials,
    unsigned* __restrict__ counter, float* __restrict__ out, int S)
{
  const int wv = threadIdx.x >> 6, lane = threadIdx.x & 63;
  const int wid = blockIdx.x * WPB + wv;            // ray id, 0..15999
  float v[10];
  #pragma unroll
  for (int j=0;j<10;j++) v[j] = 0.f;

  {
    const int b = (wid >= NRAYS) ? 1 : 0;
    const int r = wid - b*NRAYS;
    const float ox=origins[b*3+0], oy=origins[b*3+1], oz=origins[b*3+2];
    const float4 rd = rays[r];
    const int* semb = sem + b*BGRID;
    const int nchunks = (S + 63) >> 6;

    // pass 1: parallel first-hit scan, 64 steps per round.
    // Keep the breaking chunk's per-lane regs for reuse in pass 2.
    int hit = 0x7fffffff, hitflat = 0, hitgt = 0, hitc = 0;
    int lflat = 0; bool linb = false; int lgt = FREE_ID;
    for (int c=0; c<nchunks; ++c){
      const int s = (c<<6) + lane;
      bool tok;
      probe(ox,oy,oz,rd,s,S,lflat,tok,linb);
      lgt = linb ? semb[lflat] : FREE_ID;
      unsigned long long m = __ballot(linb && (lgt != FREE_ID));
      if (m){
        int f = __ffsll(m) - 1;
        hit = (c<<6) + f; hitc = c;
        hitflat = __shfl(lflat, f);
        hitgt   = __shfl(lgt, f);
        break;
      }
      if (__ballot(tok) == 0ULL) break;    // t increasing: nothing further
    }

    bool rv = false;
    if (hit != 0x7fffffff) rv = (cam[b*BGRID+hitflat] > 0);

    if (rv){
      // hit terms (uniform address -> broadcast loads)
      const float* lg = logits + (size_t)(b*BGRID+hitflat)*NCH;
      float mx, ls; lse18(lg, mx, ls);
      float pf = expf((lg[FREE_ID]-mx) - ls);
      float bh = -logf(fmaxf(1.0f - pf, 1e-6f));
      float ce = -((lg[hitgt]-mx) - ls);

      // pass 2: pre-hit free-space BCE. Chunk hitc reuses pass-1 regs.
      float npre = 0.f, spre = 0.f;
      if (hit > 0){
        for (int c=0; c<hitc; ++c){        // rare (hit usually in chunk 0)
          const int s = (c<<6) + lane;
          int flat; bool tok, inb;
          probe(ox,oy,oz,rd,s,S,flat,tok,inb);
          if (inb){
            const float* lg2 = logits + (size_t)(b*BGRID+flat)*NCH;
            float mx2, ls2; lse18(lg2, mx2, ls2);
            spre += -logf(fmaxf(expf((lg2[FREE_ID]-mx2) - ls2), 1e-6f));
            npre += 1.f;
          }
        }
        if (linb && ((hitc<<6)+lane) < hit){
          const float* lg2 = logits + (size_t)(b*BGRID+lflat)*NCH;
          float mx2, ls2; lse18(lg2, mx2, ls2);
          spre += -logf(fmaxf(expf((lg2[FREE_ID]-mx2) - ls2), 1e-6f));
          npre += 1.f;
        }
        #pragma unroll
        for (int off=32; off>=1; off>>=1){
          npre += __shfl_down(npre, off);
          spre += __shfl_down(spre, off);
        }
      }
      if (lane == 0){
        const int base = b*5;
        v[base+0]=npre; v[base+1]=spre; v[base+2]=1.f; v[base+3]=bh; v[base+4]=ce;
      }
    }
  }

  // block reduce: each wave's lane 0 writes its row; wave 0 sums in fixed order
  __shared__ float red[WPB][10];
  if (lane == 0){
    #pragma unroll
    for (int j=0;j<10;j++) red[wv][j] = v[j];
  }
  __syncthreads();
  if (wv == 0 && lane < 10){
    float s = 0.f;
    #pragma unroll
    for (int k=0;k<WPB;k++) s += red[k][lane];
    partials[(size_t)blockIdx.x*10 + lane] = s;
  }

  // ---- last-block-done fused finalize ----
  __shared__ unsigned is_last;
  __threadfence();                     // release our partials row device-wide
  __syncthreads();
  if (threadIdx.x == 0){
    unsigned old = atomicAdd(counter, 1u);
    is_last = (old == NBLOCKS-1) ? 1u : 0u;
  }
  __syncthreads();
  if (is_last){
    __threadfence();                   // acquire: invalidate stale cache
    __shared__ double sh[10][64];
    const int col = threadIdx.x >> 6;  // wave id -> column
    const int k = threadIdx.x & 63;
    if (col < 10){
      double s = 0.0;
      for (int rr=k; rr<NBLOCKS; rr+=64) s += (double)partials[(size_t)rr*10+col];
      sh[col][k] = s;
    }
    __syncthreads();
    if (threadIdx.x < 10){
      double s = 0.0;
      for (int k2=0;k2<64;k2++) s += sh[threadIdx.x][k2];
      sh[threadIdx.x][0] = s;
    }
    __syncthreads();
    if (threadIdx.x == 0){
      double sp=0, cp=0, shh=0, sc=0, ch=0;
      for (int b=0;b<NB;b++){
        double n_pre=sh[b*5+0][0], s_pre=sh[b*5+1][0];
        double n_ray=sh[b*5+2][0], s_hit=sh[b*5+3][0], s_ce=sh[b*5+4][0];
        if (n_pre>0.0){ sp += s_pre/n_pre; cp+=1.0; }
        if (n_ray>0.0){ shh += s_hit/n_ray; sc += s_ce/n_ray; ch+=1.0; }
      }
      double lp = sp / (cp>0.0?cp:1.0);
      double lh = shh / (ch>0.0?ch:1.0);
      double lc = sc / (ch>0.0?ch:1.0);
      out[0] = (float)(lp+lh+lc);
    }
  }
}

extern "C" void kernel_launch(void* const* d_in, const int* in_sizes, int n_in,
                              void* d_out, int out_size, void* d_ws, size_t ws_size,
                              hipStream_t stream)
{
  (void)in_sizes; (void)n_in; (void)out_size; (void)ws_size;
  const float* logits  = (const float*)d_in[0];
  const float* origins = (const float*)d_in[1];
  const int*   sem     = (const int*)d_in[2];
  const int*   cam     = (const int*)d_in[3];
  float* out = (float*)d_out;

  // d_ws layout: [0..255] counter block (zeroed every call),
  //              [256..40495] partials (1000*10 f32),
  //              [65536..] fallback ray-table slot.
  unsigned* counter = (unsigned*)d_ws;
  float* partials = (float*)((char*)d_ws + 256);

  const float4* d_tab = g_tab.d;
  if (!d_tab){   // constructor alloc failed: fall back to per-call H2D copy
    float4* slot = (float4*)((char*)d_ws + 65536);
    hipMemcpyAsync(slot, g_tab.h, sizeof(float4)*NRAYS,
                   hipMemcpyHostToDevice, stream);
    d_tab = slot;
  }

  hipMemsetAsync(d_ws, 0, 256, stream);   // zero the completion counter
  ray_loss_kernel<<<NBLOCKS, BLOCK, 0, stream>>>(logits, origins, sem, cam,
                                                 d_tab, partials, counter, out,
                                                 g_tab.smax);
}

// Round 4
// 50.479 us; speedup vs baseline: 5.0143x; 5.0143x over previous
//
#include <hip/hip_runtime.h>
#include <math.h>
#include <stdint.h>

#define NRAYS 8000
#define NB 2
#define GX 200
#define GY 200
#define GZ 16
#define BGRID (GX*GY*GZ)
#define NCH 18
#define FREE_ID 17
#define NWAVES (NB*NRAYS)
#define BLOCK 1024
#define WPB (BLOCK/64)
#define NBLOCKS (NWAVES/WPB)   // 1000

// ---------------- host: replicate _ray_constants() exactly ----------------
namespace {

struct MT19937 {
  uint32_t mt[624]; int mti;
  void seed(uint32_t s){
    mt[0]=s;
    for (mti=1; mti<624; ++mti)
      mt[mti] = 1812433253u*(mt[mti-1]^(mt[mti-1]>>30)) + (uint32_t)mti;
  }
  uint32_t next(){
    if (mti >= 624){
      for (int i=0;i<624;i++){
        uint32_t y = (mt[i]&0x80000000u) | (mt[(i+1)%624]&0x7fffffffu);
        mt[i] = mt[(i+397)%624] ^ (y>>1) ^ ((y&1u)? 2567483615u : 0u);
      }
      mti = 0;
    }
    uint32_t y = mt[mti++];
    y ^= y>>11; y ^= (y<<7)&2636928640u; y ^= (y<<15)&4022730752u; y ^= y>>18;
    return y;
  }
};

static uint32_t rinterval(MT19937& g, uint32_t mx){
  if (mx==0) return 0;
  uint32_t mask=mx; mask|=mask>>1; mask|=mask>>2; mask|=mask>>4; mask|=mask>>8; mask|=mask>>16;
  uint32_t v;
  do { v = g.next()&mask; } while (v>mx);
  return v;
}

static int build_table(float4* out){
  double pitch[128]; int npi=0;
  for (int k=0;k<10;k++) pitch[npi++] = -(M_PI/2.0 - atan((double)(k+1)));
  while (pitch[npi-1] < 0.21){
    double d = pitch[npi-1]-pitch[npi-2];
    pitch[npi] = pitch[npi-1]+d; ++npi;
  }
  int nrays = npi*360;   // 39*360 = 14040
  static float rx[128*360], ry[128*360], rz[128*360], rdt[128*360];
  float dtmin = 1e30f;
  for (int p=0;p<npi;p++){
    double cp = cos(pitch[p]), sp = sin(pitch[p]);
    for (int a=0;a<360;a++){
      double az = (double)a * (M_PI/180.0);
      int i = p*360+a;
      rx[i]=(float)(cp*cos(az)); ry[i]=(float)(cp*sin(az)); rz[i]=(float)sp;
      float ma = fmaxf(fabsf(rx[i]), fmaxf(fabsf(ry[i]), fabsf(rz[i])));
      ma = ma + 1e-8f;
      rdt[i] = 0.4f/ma;
      if (rdt[i] < dtmin) dtmin = rdt[i];
    }
  }
  int smax = (int)fmin(ceil(60.0/(double)dtmin), 512.0);
  static int perm[128*360];
  for (int i=0;i<nrays;i++) perm[i]=i;
  MT19937 g; g.seed(0);
  for (int i=nrays-1;i>=1;--i){
    uint32_t j = rinterval(g, (uint32_t)i);
    int tmp = perm[i]; perm[i]=perm[j]; perm[j]=tmp;
  }
  for (int i=0;i<NRAYS;i++){
    int id = perm[i];
    out[i] = make_float4(rx[id], ry[id], rz[id], rdt[id]);
  }
  return smax;
}

// Built once at library load (input-independent constant, like the reference's
// module-level _DIRS/_DT). Device copy allocated+filled OUTSIDE kernel_launch
// and outside graph capture, so the graph needs no H2D node.
struct TabHolder {
  float4* h;        // pinned (or pageable fallback) host copy
  float4* d;        // persistent device copy (null -> fallback path)
  int smax;
  TabHolder(){
    h = nullptr; d = nullptr;
    if (hipHostMalloc((void**)&h, sizeof(float4)*NRAYS, 0) != hipSuccess || !h){
      static float4 fb[NRAYS]; h = fb;
    }
    smax = build_table(h);
    float4* dp = nullptr;
    if (hipMalloc((void**)&dp, sizeof(float4)*NRAYS) == hipSuccess && dp){
      if (hipMemcpy(dp, h, sizeof(float4)*NRAYS, hipMemcpyHostToDevice) == hipSuccess)
        d = dp;
    }
  }
};
static TabHolder g_tab;

} // namespace

// ---------------- device ----------------

// step geometry; separately-rounded mul/add/div to match the reference exactly
__device__ inline void probe(float ox,float oy,float oz,const float4& rd,
                             int s,int S,int& flat,bool& tok,bool& inb)
{
  float t = __fmul_rn(rd.w, (float)s + 0.5f);
  tok = (s < S) && (t <= 60.0f);
  float px = __fadd_rn(ox, __fmul_rn(rd.x, t));
  float py = __fadd_rn(oy, __fmul_rn(rd.y, t));
  float pz = __fadd_rn(oz, __fmul_rn(rd.z, t));
  int vx = (int)floorf(__fdiv_rn(__fadd_rn(px, 40.0f), 0.4f));
  int vy = (int)floorf(__fdiv_rn(__fadd_rn(py, 40.0f), 0.4f));
  int vz = (int)floorf(__fdiv_rn(__fadd_rn(pz, 1.0f), 0.4f));
  flat = (vx*GY+vy)*GZ+vz;
  inb = tok & ((unsigned)vx < (unsigned)GX) & ((unsigned)vy < (unsigned)GY)
            & ((unsigned)vz < (unsigned)GZ);
}

__device__ inline void lse18(const float* __restrict__ lg, float& mx, float& ls){
  float m = lg[0];
  #pragma unroll
  for (int c=1;c<NCH;c++) m = fmaxf(m, lg[c]);
  float s = 0.f;
  #pragma unroll
  for (int c=0;c<NCH;c++) s += expf(lg[c]-m);
  mx = m; ls = logf(s);
}

__global__ __launch_bounds__(BLOCK) void ray_loss_kernel(
    const float* __restrict__ logits, const float* __restrict__ origins,
    const int* __restrict__ sem, const int* __restrict__ cam,
    const float4* __restrict__ rays, float* __restrict__ partials,
    unsigned* __restrict__ counter, float* __restrict__ out, int S)
{
  const int wv = threadIdx.x >> 6, lane = threadIdx.x & 63;
  const int wid = blockIdx.x * WPB + wv;            // ray id, 0..15999
  float v[10];
  #pragma unroll
  for (int j=0;j<10;j++) v[j] = 0.f;

  {
    const int b = (wid >= NRAYS) ? 1 : 0;
    const int r = wid - b*NRAYS;
    const float ox=origins[b*3+0], oy=origins[b*3+1], oz=origins[b*3+2];
    const float4 rd = rays[r];
    const int* semb = sem + b*BGRID;
    const int nchunks = (S + 63) >> 6;

    // pass 1: parallel first-hit scan, 64 steps per round.
    // Keep the breaking chunk's per-lane regs for reuse in pass 2.
    int hit = 0x7fffffff, hitflat = 0, hitgt = 0, hitc = 0;
    int lflat = 0; bool linb = false; int lgt = FREE_ID;
    for (int c=0; c<nchunks; ++c){
      const int s = (c<<6) + lane;
      bool tok;
      probe(ox,oy,oz,rd,s,S,lflat,tok,linb);
      lgt = linb ? semb[lflat] : FREE_ID;
      unsigned long long m = __ballot(linb && (lgt != FREE_ID));
      if (m){
        int f = __ffsll(m) - 1;
        hit = (c<<6) + f; hitc = c;
        hitflat = __shfl(lflat, f);
        hitgt   = __shfl(lgt, f);
        break;
      }
      if (__ballot(tok) == 0ULL) break;    // t increasing: nothing further
    }

    bool rv = false;
    if (hit != 0x7fffffff) rv = (cam[b*BGRID+hitflat] > 0);

    if (rv){
      // hit terms (uniform address -> broadcast loads)
      const float* lg = logits + (size_t)(b*BGRID+hitflat)*NCH;
      float mx, ls; lse18(lg, mx, ls);
      float pf = expf((lg[FREE_ID]-mx) - ls);
      float bh = -logf(fmaxf(1.0f - pf, 1e-6f));
      float ce = -((lg[hitgt]-mx) - ls);

      // pass 2: pre-hit free-space BCE. Chunk hitc reuses pass-1 regs.
      float npre = 0.f, spre = 0.f;
      if (hit > 0){
        for (int c=0; c<hitc; ++c){        // rare (hit usually in chunk 0)
          const int s = (c<<6) + lane;
          int flat; bool tok, inb;
          probe(ox,oy,oz,rd,s,S,flat,tok,inb);
          if (inb){
            const float* lg2 = logits + (size_t)(b*BGRID+flat)*NCH;
            float mx2, ls2; lse18(lg2, mx2, ls2);
            spre += -logf(fmaxf(expf((lg2[FREE_ID]-mx2) - ls2), 1e-6f));
            npre += 1.f;
          }
        }
        if (linb && ((hitc<<6)+lane) < hit){
          const float* lg2 = logits + (size_t)(b*BGRID+lflat)*NCH;
          float mx2, ls2; lse18(lg2, mx2, ls2);
          spre += -logf(fmaxf(expf((lg2[FREE_ID]-mx2) - ls2), 1e-6f));
          npre += 1.f;
        }
        #pragma unroll
        for (int off=32; off>=1; off>>=1){
          npre += __shfl_down(npre, off);
          spre += __shfl_down(spre, off);
        }
      }
      if (lane == 0){
        const int base = b*5;
        v[base+0]=npre; v[base+1]=spre; v[base+2]=1.f; v[base+3]=bh; v[base+4]=ce;
      }
    }
  }

  // block reduce: each wave's lane 0 writes its row to LDS
  __shared__ float red[WPB][10];
  if (lane == 0){
    #pragma unroll
    for (int j=0;j<10;j++) red[wv][j] = v[j];
  }
  __syncthreads();

  // ---- fused finalize, canonical single-publisher pattern ----
  // ONE thread per block: sum LDS rows, store the partial row itself,
  // ONE __threadfence (device release), then the counter atomic.
  __shared__ unsigned is_last;
  if (threadIdx.x == 0){
    #pragma unroll
    for (int j=0;j<10;j++){
      float s = 0.f;
      #pragma unroll
      for (int k=0;k<WPB;k++) s += red[k][j];
      partials[(size_t)blockIdx.x*10 + j] = s;
    }
    __threadfence();                       // publish this block's row
    unsigned old = atomicAdd(counter, 1u);
    is_last = (old == NBLOCKS-1) ? 1u : 0u;
  }
  __syncthreads();

  if (is_last){
    __threadfence();                       // acquire: drop stale L1/L2 lines
    __shared__ double sh[10][64];
    const int col = threadIdx.x >> 6;      // wave id -> column
    const int k = threadIdx.x & 63;
    if (col < 10){
      double s = 0.0;
      for (int rr=k; rr<NBLOCKS; rr+=64) s += (double)partials[(size_t)rr*10+col];
      sh[col][k] = s;
    }
    __syncthreads();
    if (threadIdx.x < 10){
      double s = 0.0;
      for (int k2=0;k2<64;k2++) s += sh[threadIdx.x][k2];
      sh[threadIdx.x][0] = s;
    }
    __syncthreads();
    if (threadIdx.x == 0){
      double sp=0, cp=0, shh=0, sc=0, ch=0;
      for (int b=0;b<NB;b++){
        double n_pre=sh[b*5+0][0], s_pre=sh[b*5+1][0];
        double n_ray=sh[b*5+2][0], s_hit=sh[b*5+3][0], s_ce=sh[b*5+4][0];
        if (n_pre>0.0){ sp += s_pre/n_pre; cp+=1.0; }
        if (n_ray>0.0){ shh += s_hit/n_ray; sc += s_ce/n_ray; ch+=1.0; }
      }
      double lp = sp / (cp>0.0?cp:1.0);
      double lh = shh / (ch>0.0?ch:1.0);
      double lc = sc / (ch>0.0?ch:1.0);
      out[0] = (float)(lp+lh+lc);
    }
  }
}

extern "C" void kernel_launch(void* const* d_in, const int* in_sizes, int n_in,
                              void* d_out, int out_size, void* d_ws, size_t ws_size,
                              hipStream_t stream)
{
  (void)in_sizes; (void)n_in; (void)out_size; (void)ws_size;
  const float* logits  = (const float*)d_in[0];
  const float* origins = (const float*)d_in[1];
  const int*   sem     = (const int*)d_in[2];
  const int*   cam     = (const int*)d_in[3];
  float* out = (float*)d_out;

  // d_ws layout: [0..255] counter block (zeroed every call),
  //              [256..40495] partials (1000*10 f32),
  //              [65536..] fallback ray-table slot.
  unsigned* counter = (unsigned*)d_ws;
  float* partials = (float*)((char*)d_ws + 256);

  const float4* d_tab = g_tab.d;
  if (!d_tab){   // constructor alloc failed: fall back to per-call H2D copy
    float4* slot = (float4*)((char*)d_ws + 65536);
    hipMemcpyAsync(slot, g_tab.h, sizeof(float4)*NRAYS,
                   hipMemcpyHostToDevice, stream);
    d_tab = slot;
  }

  hipMemsetAsync(d_ws, 0, 256, stream);   // zero the completion counter
  ray_loss_kernel<<<NBLOCKS, BLOCK, 0, stream>>>(logits, origins, sem, cam,
                                                 d_tab, partials, counter, out,
                                                 g_tab.smax);
}

// Round 5
// 22.257 us; speedup vs baseline: 11.3723x; 2.2680x over previous
//
#include <hip/hip_runtime.h>
#include <math.h>
#include <stdint.h>

#define NRAYS 8000
#define NB 2
#define GX 200
#define GY 200
#define GZ 16
#define BGRID (GX*GY*GZ)
#define NCH 18
#define FREE_ID 17
#define NWAVES (NB*NRAYS)
#define BLOCK 1024
#define WPB (BLOCK/64)
#define NBLOCKS (NWAVES/WPB)   // 1000
#define RBLOCK 256

// ---------------- host: replicate _ray_constants() exactly ----------------
namespace {

struct MT19937 {
  uint32_t mt[624]; int mti;
  void seed(uint32_t s){
    mt[0]=s;
    for (mti=1; mti<624; ++mti)
      mt[mti] = 1812433253u*(mt[mti-1]^(mt[mti-1]>>30)) + (uint32_t)mti;
  }
  uint32_t next(){
    if (mti >= 624){
      for (int i=0;i<624;i++){
        uint32_t y = (mt[i]&0x80000000u) | (mt[(i+1)%624]&0x7fffffffu);
        mt[i] = mt[(i+397)%624] ^ (y>>1) ^ ((y&1u)? 2567483615u : 0u);
      }
      mti = 0;
    }
    uint32_t y = mt[mti++];
    y ^= y>>11; y ^= (y<<7)&2636928640u; y ^= (y<<15)&4022730752u; y ^= y>>18;
    return y;
  }
};

static uint32_t rinterval(MT19937& g, uint32_t mx){
  if (mx==0) return 0;
  uint32_t mask=mx; mask|=mask>>1; mask|=mask>>2; mask|=mask>>4; mask|=mask>>8; mask|=mask>>16;
  uint32_t v;
  do { v = g.next()&mask; } while (v>mx);
  return v;
}

static int build_table(float4* out){
  double pitch[128]; int npi=0;
  for (int k=0;k<10;k++) pitch[npi++] = -(M_PI/2.0 - atan((double)(k+1)));
  while (pitch[npi-1] < 0.21){
    double d = pitch[npi-1]-pitch[npi-2];
    pitch[npi] = pitch[npi-1]+d; ++npi;
  }
  int nrays = npi*360;   // 39*360 = 14040
  static float rx[128*360], ry[128*360], rz[128*360], rdt[128*360];
  float dtmin = 1e30f;
  for (int p=0;p<npi;p++){
    double cp = cos(pitch[p]), sp = sin(pitch[p]);
    for (int a=0;a<360;a++){
      double az = (double)a * (M_PI/180.0);
      int i = p*360+a;
      rx[i]=(float)(cp*cos(az)); ry[i]=(float)(cp*sin(az)); rz[i]=(float)sp;
      float ma = fmaxf(fabsf(rx[i]), fmaxf(fabsf(ry[i]), fabsf(rz[i])));
      ma = ma + 1e-8f;
      rdt[i] = 0.4f/ma;
      if (rdt[i] < dtmin) dtmin = rdt[i];
    }
  }
  int smax = (int)fmin(ceil(60.0/(double)dtmin), 512.0);
  static int perm[128*360];
  for (int i=0;i<nrays;i++) perm[i]=i;
  MT19937 g; g.seed(0);
  for (int i=nrays-1;i>=1;--i){
    uint32_t j = rinterval(g, (uint32_t)i);
    int tmp = perm[i]; perm[i]=perm[j]; perm[j]=tmp;
  }
  for (int i=0;i<NRAYS;i++){
    int id = perm[i];
    out[i] = make_float4(rx[id], ry[id], rz[id], rdt[id]);
  }
  return smax;
}

// Built once at library load (input-independent constant, like the reference's
// module-level _DIRS/_DT). Device copy allocated+filled OUTSIDE kernel_launch
// and outside graph capture, so the graph needs no H2D node.
struct TabHolder {
  float4* h;        // pinned (or pageable fallback) host copy
  float4* d;        // persistent device copy (null -> fallback path)
  int smax;
  TabHolder(){
    h = nullptr; d = nullptr;
    if (hipHostMalloc((void**)&h, sizeof(float4)*NRAYS, 0) != hipSuccess || !h){
      static float4 fb[NRAYS]; h = fb;
    }
    smax = build_table(h);
    float4* dp = nullptr;
    if (hipMalloc((void**)&dp, sizeof(float4)*NRAYS) == hipSuccess && dp){
      if (hipMemcpy(dp, h, sizeof(float4)*NRAYS, hipMemcpyHostToDevice) == hipSuccess)
        d = dp;
    }
  }
};
static TabHolder g_tab;

} // namespace

// ---------------- device ----------------

// step geometry; separately-rounded mul/add/div to match the reference exactly
__device__ inline void probe(float ox,float oy,float oz,const float4& rd,
                             int s,int S,int& flat,bool& tok,bool& inb)
{
  float t = __fmul_rn(rd.w, (float)s + 0.5f);
  tok = (s < S) && (t <= 60.0f);
  float px = __fadd_rn(ox, __fmul_rn(rd.x, t));
  float py = __fadd_rn(oy, __fmul_rn(rd.y, t));
  float pz = __fadd_rn(oz, __fmul_rn(rd.z, t));
  int vx = (int)floorf(__fdiv_rn(__fadd_rn(px, 40.0f), 0.4f));
  int vy = (int)floorf(__fdiv_rn(__fadd_rn(py, 40.0f), 0.4f));
  int vz = (int)floorf(__fdiv_rn(__fadd_rn(pz, 1.0f), 0.4f));
  flat = (vx*GY+vy)*GZ+vz;
  inb = tok & ((unsigned)vx < (unsigned)GX) & ((unsigned)vy < (unsigned)GY)
            & ((unsigned)vz < (unsigned)GZ);
}

__device__ inline void lse18(const float* __restrict__ lg, float& mx, float& ls){
  float m = lg[0];
  #pragma unroll
  for (int c=1;c<NCH;c++) m = fmaxf(m, lg[c]);
  float s = 0.f;
  #pragma unroll
  for (int c=0;c<NCH;c++) s += expf(lg[c]-m);
  mx = m; ls = logf(s);
}

__global__ __launch_bounds__(BLOCK) void ray_loss_kernel(
    const float* __restrict__ logits, const float* __restrict__ origins,
    const int* __restrict__ sem, const int* __restrict__ cam,
    const float4* __restrict__ rays, float* __restrict__ partials, int S)
{
  const int wv = threadIdx.x >> 6, lane = threadIdx.x & 63;
  const int wid = blockIdx.x * WPB + wv;            // ray id, 0..15999
  float v[10];
  #pragma unroll
  for (int j=0;j<10;j++) v[j] = 0.f;

  {
    const int b = (wid >= NRAYS) ? 1 : 0;
    const int r = wid - b*NRAYS;
    const float ox=origins[b*3+0], oy=origins[b*3+1], oz=origins[b*3+2];
    const float4 rd = rays[r];
    const int* semb = sem + b*BGRID;
    const int nchunks = (S + 63) >> 6;

    // pass 1: parallel first-hit scan, 64 steps per round.
    // Keep the breaking chunk's per-lane regs for reuse in pass 2.
    int hit = 0x7fffffff, hitflat = 0, hitgt = 0, hitc = 0;
    int lflat = 0; bool linb = false; int lgt = FREE_ID;
    for (int c=0; c<nchunks; ++c){
      const int s = (c<<6) + lane;
      bool tok;
      probe(ox,oy,oz,rd,s,S,lflat,tok,linb);
      lgt = linb ? semb[lflat] : FREE_ID;
      unsigned long long m = __ballot(linb && (lgt != FREE_ID));
      if (m){
        int f = __ffsll(m) - 1;
        hit = (c<<6) + f; hitc = c;
        hitflat = __shfl(lflat, f);
        hitgt   = __shfl(lgt, f);
        break;
      }
      if (__ballot(tok) == 0ULL) break;    // t increasing: nothing further
    }

    bool rv = false;
    if (hit != 0x7fffffff) rv = (cam[b*BGRID+hitflat] > 0);

    if (rv){
      // hit terms (uniform address -> broadcast loads)
      const float* lg = logits + (size_t)(b*BGRID+hitflat)*NCH;
      float mx, ls; lse18(lg, mx, ls);
      float pf = expf((lg[FREE_ID]-mx) - ls);
      float bh = -logf(fmaxf(1.0f - pf, 1e-6f));
      float ce = -((lg[hitgt]-mx) - ls);

      // pass 2: pre-hit free-space BCE. Chunk hitc reuses pass-1 regs.
      float npre = 0.f, spre = 0.f;
      if (hit > 0){
        for (int c=0; c<hitc; ++c){        // rare (hit usually in chunk 0)
          const int s = (c<<6) + lane;
          int flat; bool tok, inb;
          probe(ox,oy,oz,rd,s,S,flat,tok,inb);
          if (inb){
            const float* lg2 = logits + (size_t)(b*BGRID+flat)*NCH;
            float mx2, ls2; lse18(lg2, mx2, ls2);
            spre += -logf(fmaxf(expf((lg2[FREE_ID]-mx2) - ls2), 1e-6f));
            npre += 1.f;
          }
        }
        if (linb && ((hitc<<6)+lane) < hit){
          const float* lg2 = logits + (size_t)(b*BGRID+lflat)*NCH;
          float mx2, ls2; lse18(lg2, mx2, ls2);
          spre += -logf(fmaxf(expf((lg2[FREE_ID]-mx2) - ls2), 1e-6f));
          npre += 1.f;
        }
        #pragma unroll
        for (int off=32; off>=1; off>>=1){
          npre += __shfl_down(npre, off);
          spre += __shfl_down(spre, off);
        }
      }
      if (lane == 0){
        const int base = b*5;
        v[base+0]=npre; v[base+1]=spre; v[base+2]=1.f; v[base+3]=bh; v[base+4]=ce;
      }
    }
  }

  // block reduce: each wave's lane 0 writes its row; wave 0 sums in fixed
  // order and publishes with a plain store. The kernel boundary (full memory
  // drain before the dependent finalize dispatch) is the release/acquire —
  // no fences, no atomics, no counter (R3/R4 showed device-scope fences at
  // 1000-block scale cost ~30 µs on gfx950's non-coherent L2s).
  __shared__ float red[WPB][10];
  if (lane == 0){
    #pragma unroll
    for (int j=0;j<10;j++) red[wv][j] = v[j];
  }
  __syncthreads();
  if (wv == 0 && lane < 10){
    float s = 0.f;
    #pragma unroll
    for (int k=0;k<WPB;k++) s += red[k][lane];
    partials[(size_t)blockIdx.x*10 + lane] = s;
  }
}

__global__ __launch_bounds__(RBLOCK) void finalize_kernel(
    const float* __restrict__ partials, float* __restrict__ out, int nblocks)
{
  __shared__ double acc[RBLOCK][10];
  double a[10];
  #pragma unroll
  for (int j=0;j<10;j++) a[j]=0.0;
  for (int r = threadIdx.x; r < nblocks; r += RBLOCK){
    #pragma unroll
    for (int j=0;j<10;j++) a[j] += (double)partials[(size_t)r*10+j];
  }
  #pragma unroll
  for (int j=0;j<10;j++) acc[threadIdx.x][j]=a[j];
  __syncthreads();
  for (int off=RBLOCK/2; off>=1; off>>=1){
    if ((int)threadIdx.x < off){
      #pragma unroll
      for (int j=0;j<10;j++) acc[threadIdx.x][j]+=acc[threadIdx.x+off][j];
    }
    __syncthreads();
  }
  if (threadIdx.x==0){
    double sp=0, cp=0, sh=0, sc=0, ch=0;
    for (int b=0;b<NB;b++){
      double n_pre=acc[0][b*5+0], s_pre=acc[0][b*5+1];
      double n_ray=acc[0][b*5+2], s_hit=acc[0][b*5+3], s_ce=acc[0][b*5+4];
      if (n_pre>0.0){ sp += s_pre/n_pre; cp+=1.0; }
      if (n_ray>0.0){ sh += s_hit/n_ray; sc += s_ce/n_ray; ch+=1.0; }
    }
    double lp = sp / (cp>0.0?cp:1.0);
    double lh = sh / (ch>0.0?ch:1.0);
    double lc = sc / (ch>0.0?ch:1.0);
    out[0] = (float)(lp+lh+lc);
  }
}

extern "C" void kernel_launch(void* const* d_in, const int* in_sizes, int n_in,
                              void* d_out, int out_size, void* d_ws, size_t ws_size,
                              hipStream_t stream)
{
  (void)in_sizes; (void)n_in; (void)out_size; (void)ws_size;
  const float* logits  = (const float*)d_in[0];
  const float* origins = (const float*)d_in[1];
  const int*   sem     = (const int*)d_in[2];
  const int*   cam     = (const int*)d_in[3];
  float* out = (float*)d_out;

  // d_ws layout: [0..40kB) partials (1000*10 f32, fully overwritten every
  // call by all 1000 blocks), [64kB..) fallback ray-table slot.
  float* partials = (float*)d_ws;

  const float4* d_tab = g_tab.d;
  if (!d_tab){   // constructor alloc failed: fall back to per-call H2D copy
    float4* slot = (float4*)((char*)d_ws + 65536);
    hipMemcpyAsync(slot, g_tab.h, sizeof(float4)*NRAYS,
                   hipMemcpyHostToDevice, stream);
    d_tab = slot;
  }

  ray_loss_kernel<<<NBLOCKS, BLOCK, 0, stream>>>(logits, origins, sem, cam,
                                                 d_tab, partials, g_tab.smax);
  finalize_kernel<<<1, RBLOCK, 0, stream>>>(partials, out, NBLOCKS);
}